// Round 9
// baseline (405.586 us; speedup 1.0000x reference)
//
#include <hip/hip_runtime.h>
#include <hip/hip_bf16.h>
#include <stdint.h>

// ---------- types ----------
typedef __bf16 bf16_t;
typedef __attribute__((ext_vector_type(8))) __bf16 bf16x8;   // MFMA A/B frag (4 VGPR)
typedef __attribute__((ext_vector_type(4))) float floatx4;   // 16x16 C frag
typedef __attribute__((ext_vector_type(16))) float f32x16;   // 32x32 C frag
typedef __attribute__((ext_vector_type(2))) int i32x2;

typedef __attribute__((address_space(1))) const unsigned int gu32_t;
typedef __attribute__((address_space(3))) unsigned int lu32_t;

// async global->LDS, 16B per lane; LDS dest = wave-uniform base + lane*16
__device__ __forceinline__ void async16(const void* g, void* l) {
    __builtin_amdgcn_global_load_lds((gu32_t*)g, (lu32_t*)l, 16, 0, 0);
}

__device__ __forceinline__ uint32_t pack2(float lo, float hi) {
    union { bf16_t h[2]; uint32_t u; } cv;
    cv.h[0] = (bf16_t)lo; cv.h[1] = (bf16_t)hi;
    return cv.u;
}

// ---------- fp32 -> bf16 convert ----------
__global__ __launch_bounds__(256) void cvt_f32_bf16(const float* __restrict__ in,
                                                    bf16_t* __restrict__ out) {
    int i = (blockIdx.x * 256 + threadIdx.x) * 8;
    float4 a = *(const float4*)(in + i);
    float4 b = *(const float4*)(in + i + 4);
    bf16x8 v;
    v[0] = (bf16_t)a.x; v[1] = (bf16_t)a.y; v[2] = (bf16_t)a.z; v[3] = (bf16_t)a.w;
    v[4] = (bf16_t)b.x; v[5] = (bf16_t)b.y; v[6] = (bf16_t)b.z; v[7] = (bf16_t)b.w;
    *(bf16x8*)(out + i) = v;
}

// 4 equal-size weight matrices in one dispatch (blockIdx.y selects source)
__global__ __launch_bounds__(256) void cvt4_f32_bf16(const float* __restrict__ w0,
                                                     const float* __restrict__ w1,
                                                     const float* __restrict__ w2,
                                                     const float* __restrict__ w3,
                                                     bf16_t* __restrict__ out,
                                                     int elems) {
    const float* srcs[4] = {w0, w1, w2, w3};
    const float* in = srcs[blockIdx.y];
    bf16_t* o = out + (size_t)blockIdx.y * elems;
    int i = (blockIdx.x * 256 + threadIdx.x) * 8;
    float4 a = *(const float4*)(in + i);
    float4 b = *(const float4*)(in + i + 4);
    bf16x8 v;
    v[0] = (bf16_t)a.x; v[1] = (bf16_t)a.y; v[2] = (bf16_t)a.z; v[3] = (bf16_t)a.w;
    v[4] = (bf16_t)b.x; v[5] = (bf16_t)b.y; v[6] = (bf16_t)b.z; v[7] = (bf16_t)b.w;
    *(bf16x8*)(o + i) = v;
}

// ---------- GEMM 128x128 (m97 structure, measured-good for 2048-dim V/O) ---
template <bool OUT_F32, bool BIAS_ROW>
__global__ __launch_bounds__(256) void gemm_bt(const bf16_t* __restrict__ A,
                                               const bf16_t* __restrict__ B,
                                               const float* __restrict__ bias,
                                               const float* __restrict__ bias2,
                                               int nsplit, float scaleA, float scaleB,
                                               float* __restrict__ Cf,
                                               bf16_t* __restrict__ Cb,
                                               int M, int N, int K, int ldc) {
    __shared__ bf16_t As[128 * 64];
    __shared__ bf16_t Bs[128 * 64];
    const int tid = threadIdx.x;
    const int wave = tid >> 6, lane = tid & 63;
    const int quad = lane >> 4, l16 = lane & 15;
    const int wm = (wave >> 1) * 64, wn = (wave & 1) * 64;
    const int tm = blockIdx.x * 128, tn = blockIdx.y * 128;

    floatx4 acc[4][4];
#pragma unroll
    for (int i = 0; i < 4; ++i)
#pragma unroll
        for (int j = 0; j < 4; ++j) acc[i][j] = floatx4{0.f, 0.f, 0.f, 0.f};

    const bf16_t* Abase = A + (size_t)tm * K;
    const bf16_t* Bbase = B + (size_t)tn * K;
    const int sw = l16 & 7;

    for (int kk = 0; kk < K; kk += 64) {
#pragma unroll
        for (int it = 0; it < 4; ++it) {
            int chunk = it * 256 + tid;
            int r = chunk >> 3, c = chunk & 7;
            int c2 = c ^ (r & 7);
            async16(Abase + r * K + kk + c2 * 8, As + (it * 256 + wave * 64) * 8);
            async16(Bbase + r * K + kk + c2 * 8, Bs + (it * 256 + wave * 64) * 8);
        }
        __syncthreads();
#pragma unroll
        for (int ks = 0; ks < 2; ++ks) {
            bf16x8 af[4], bf[4];
#pragma unroll
            for (int mt = 0; mt < 4; ++mt)
                af[mt] = *(const bf16x8*)(As + (wm + mt * 16 + l16) * 64 +
                                          ((ks * 4 + quad) ^ sw) * 8);
#pragma unroll
            for (int nt = 0; nt < 4; ++nt)
                bf[nt] = *(const bf16x8*)(Bs + (wn + nt * 16 + l16) * 64 +
                                          ((ks * 4 + quad) ^ sw) * 8);
#pragma unroll
            for (int mt = 0; mt < 4; ++mt)
#pragma unroll
                for (int nt = 0; nt < 4; ++nt)
                    acc[mt][nt] = __builtin_amdgcn_mfma_f32_16x16x32_bf16(af[mt], bf[nt],
                                                                          acc[mt][nt], 0, 0, 0);
        }
        __syncthreads();
    }
#pragma unroll
    for (int mt = 0; mt < 4; ++mt)
#pragma unroll
        for (int nt = 0; nt < 4; ++nt)
#pragma unroll
            for (int r = 0; r < 4; ++r) {
                int row = tm + wm + mt * 16 + quad * 4 + r;
                int col = tn + wn + nt * 16 + l16;
                float bv = BIAS_ROW ? bias[row]
                                    : (col < nsplit ? bias[col] : bias2[col - nsplit]);
                float v = acc[mt][nt][r] + bv;
                if (!BIAS_ROW) v *= (col < nsplit ? scaleA : scaleB);
                if (OUT_F32) Cf[(size_t)row * ldc + col] = v;
                else Cb[(size_t)row * ldc + col] = (bf16_t)v;
            }
}

// ---------- GEMM 256x256, 8-phase counted schedule (QK projection only) ----
// EXACT R4 version (verified -25us vs gemm_bt). R8's ds-prefetch variant was
// +8us (m133-consistent: reg prefetch on barrier-synced loop is null/neg) --
// reverted. R7's st_16x32 swizzle was +17us (wrong slot spread) -- reverted.
template <bool OUT_F32>
__global__ __launch_bounds__(512, 2) void gemm256(const bf16_t* __restrict__ A,
                                                  const bf16_t* __restrict__ B,
                                                  const float* __restrict__ bias,
                                                  const float* __restrict__ bias2,
                                                  int nsplit, float scaleA, float scaleB,
                                                  float* __restrict__ Cf,
                                                  bf16_t* __restrict__ Cb,
                                                  int M, int N, int K, int ldc) {
    __shared__ bf16_t As[2][256 * 64];   // 64 KB
    __shared__ bf16_t Bs[2][256 * 64];   // 64 KB
    const int tid = threadIdx.x;
    const int wave = tid >> 6, lane = tid & 63;
    const int quad = lane >> 4, l16 = lane & 15;
    const int wr = wave >> 2, wc = wave & 3;           // 2 x 4 wave grid
    const int nbx = M >> 8;
    const int nwg = nbx * (N >> 8);
    const int xcd = blockIdx.x & 7, idx = blockIdx.x >> 3;
    const int per = nwg >> 3;                           // nwg % 8 == 0 here
    const int wg = xcd * per + idx;
    const int tm = (wg % nbx) * 256, tn = (wg / nbx) * 256;

    floatx4 acc[8][4];
#pragma unroll
    for (int i = 0; i < 8; ++i)
#pragma unroll
        for (int j = 0; j < 4; ++j) acc[i][j] = floatx4{0.f, 0.f, 0.f, 0.f};

    const bf16_t* Abase = A + (size_t)tm * K;
    const bf16_t* Bbase = B + (size_t)tn * K;
    const int sw = l16 & 7;
    const int NT = K >> 6;

    auto stageA = [&](int kk, int b) {
#pragma unroll
        for (int it = 0; it < 4; ++it) {
            int chunk = it * 512 + tid;            // 256 rows x 8 chunks
            int r = chunk >> 3, c = chunk & 7;
            int c2 = c ^ (r & 7);
            async16(Abase + (size_t)r * K + kk + c2 * 8, As[b] + chunk * 8);
        }
    };
    auto stageB = [&](int kk, int b) {
#pragma unroll
        for (int it = 0; it < 4; ++it) {
            int chunk = it * 512 + tid;
            int r = chunk >> 3, c = chunk & 7;
            int c2 = c ^ (r & 7);
            async16(Bbase + (size_t)r * K + kk + c2 * 8, Bs[b] + chunk * 8);
        }
    };

    // prologue: tile 0 fully staged & visible
    stageA(0, 0);
    stageB(0, 0);
    asm volatile("s_waitcnt vmcnt(0)" ::: "memory");
    __builtin_amdgcn_s_barrier();
    __builtin_amdgcn_sched_barrier(0);

    for (int t = 0; t < NT; ++t) {
        const int cur = t & 1;
        const bf16_t* Asb = As[cur];
        const bf16_t* Bsb = Bs[cur];
        const int nk = (t + 1) << 6;
        const bool more = (t + 1 < NT);
#pragma unroll
        for (int p = 0; p < 4; ++p) {
            const int mh = p >> 1, nh = p & 1;     // quadrant: rows mh*64, cols nh*32
            bf16x8 af[4][2], bg[2][2];
#pragma unroll
            for (int mt = 0; mt < 4; ++mt) {
                int row = wr * 128 + mh * 64 + mt * 16 + l16;
#pragma unroll
                for (int ks = 0; ks < 2; ++ks)
                    af[mt][ks] = *(const bf16x8*)(Asb + row * 64 + ((ks * 4 + quad) ^ sw) * 8);
            }
#pragma unroll
            for (int nt = 0; nt < 2; ++nt) {
                int col = wc * 64 + nh * 32 + nt * 16 + l16;
#pragma unroll
                for (int ks = 0; ks < 2; ++ks)
                    bg[nt][ks] = *(const bf16x8*)(Bsb + col * 64 + ((ks * 4 + quad) ^ sw) * 8);
            }
            if (more) {                            // issue-early: full tile ahead
                if (p == 0) stageA(nk, cur ^ 1);
                else if (p == 1) stageB(nk, cur ^ 1);
            }
            __builtin_amdgcn_s_barrier();
            asm volatile("s_waitcnt lgkmcnt(0)" ::: "memory");
            __builtin_amdgcn_sched_barrier(0);
            __builtin_amdgcn_s_setprio(1);
#pragma unroll
            for (int ks = 0; ks < 2; ++ks)
#pragma unroll
                for (int mt = 0; mt < 4; ++mt)
#pragma unroll
                    for (int nt = 0; nt < 2; ++nt)
                        acc[mh * 4 + mt][nh * 2 + nt] =
                            __builtin_amdgcn_mfma_f32_16x16x32_bf16(
                                af[mt][ks], bg[nt][ks], acc[mh * 4 + mt][nh * 2 + nt], 0, 0, 0);
            __builtin_amdgcn_s_setprio(0);
            if (p == 3 && more)                    // boundary: next tile landed
                asm volatile("s_waitcnt vmcnt(0)" ::: "memory");
            __builtin_amdgcn_s_barrier();
            __builtin_amdgcn_sched_barrier(0);
        }
    }

#pragma unroll
    for (int am = 0; am < 8; ++am)
#pragma unroll
        for (int an = 0; an < 4; ++an)
#pragma unroll
            for (int r = 0; r < 4; ++r) {
                int row = tm + wr * 128 + (am >> 2) * 64 + (am & 3) * 16 + quad * 4 + r;
                int col = tn + wc * 64 + (an >> 1) * 32 + (an & 1) * 16 + l16;
                float bv = col < nsplit ? bias[col] : bias2[col - nsplit];
                float v = (acc[am][an][r] + bv) * (col < nsplit ? scaleA : scaleB);
                if (OUT_F32) Cf[(size_t)row * ldc + col] = v;
                else Cb[(size_t)row * ldc + col] = (bf16_t)v;
            }
}

// ---------- flash attention: R3 structure at 512 threads / 128 q-rows ------
// R14: two q-tiles merged into one block -> 8 waves share ONE staged K/V copy.
// Per-CU staging pressure halves: LDS writes 64KB->32KB per kt (~25% of the
// kt budget), K/V L2 read traffic 19 TB/s -> ~9.5 (was 55% of L2 ceiling).
// NOT R1's failure mode: launch_bounds(512,2) caps regs at 256 (R1's (512,4)
// capped at 64 -> acc spills, FETCH 585MB). ~170 live regs fit -> no spill.
// Per-wave code identical to the measured-best R3 structure (wq now 0..3);
// 512-thread epilogue layout (Op 4x128x32 fp32 = 64KB exact) was
// harness-verified correct in R1. Same 2 waves/SIMD occupancy.
#define KELEMS (64 * 128)   // 16 KB per K buffer
#define VELEMS (128 * 64)   // 16 KB per V buffer
__global__ __launch_bounds__(512, 2) void flash_attn(const bf16_t* __restrict__ Qp,
                                                     const bf16_t* __restrict__ Kp,
                                                     const bf16_t* __restrict__ Vt,
                                                     bf16_t* __restrict__ O) {
    __shared__ bf16_t smem[2 * KELEMS + 2 * VELEMS];  // K0 K1 V0 V1 = 64 KB
    const int tid = threadIdx.x;
    const int wv = tid >> 6, lane = tid & 63;
    const int hi = lane >> 5, l32 = lane & 31;
    const int wq = wv >> 1, wk = wv & 1;   // 4 q-subtiles x 2 k-halves
    const int LD = 4096, T = 4096, S = 2048, HO = 2048;

    // XCD-aware decode: 512 blocks = 16 qt x 32 grp; gid&7 = XCD.
    const int gid = blockIdx.x;
    const int kq = gid >> 3;
    const int qt = kq & 15;                       // q-tile 0..15 (128 rows)
    const int grp = (gid & 7) + 8 * (kq >> 4);    // group 0..31
    const int hd = grp & 15, bt = grp >> 4;

    const int qrow0 = bt * S + qt * 128;
    const int krow0 = bt * S;
    const int hoff = hd * 128;
    const int sw7 = l32 & 7;
    const int swK = l32 & 15;

    // Q B-frags: B[k][q=l32], k = 16*ks + 8*hi + j, for q-rows wq*32..+32
    bf16x8 qf[8];
    const bf16_t* qptr = Qp + (size_t)(qrow0 + wq * 32 + l32) * LD + hoff + hi * 8;
#pragma unroll
    for (int ks = 0; ks < 8; ++ks) qf[ks] = *(const bf16x8*)(qptr + ks * 16);

    float l_i = 0.f;   // linear softmax denominator partial
    f32x16 Oacc[4];    // O^T partial: rows d (128), col q = l32 (AGPR-resident)
#pragma unroll
    for (int dt = 0; dt < 4; ++dt)
#pragma unroll
        for (int r = 0; r < 16; ++r) Oacc[dt][r] = 0.f;

    auto stageK = [&](int kt, int b) {
        int kb = krow0 + kt * 64;
        bf16_t* Ks = smem + b * KELEMS;
#pragma unroll
        for (int it = 0; it < 2; ++it) {
            int chunk = it * 512 + tid;          // 64 rows x 16 slots
            int r = chunk >> 4, c = chunk & 15;
            int c2 = c ^ (r & 15);
            async16(Kp + (size_t)(kb + r) * LD + hoff + c2 * 8, Ks + chunk * 8);
        }
    };
    auto stageV = [&](int kt, int b) {
        int kb = krow0 + kt * 64;
        bf16_t* Vts = smem + 2 * KELEMS + b * VELEMS;
#pragma unroll
        for (int it = 0; it < 2; ++it) {
            int chunk = it * 512 + tid;          // 128 rows x 8 slots
            int r = chunk >> 3, c = chunk & 7;
            int c2 = c ^ (r & 7);
            async16(Vt + (size_t)(hoff + r) * T + kb + c2 * 8, Vts + chunk * 8);
        }
    };

    // PV step for tile whose packed P is in pk[], V in buffer vb
    auto pv = [&](const uint32_t* pk, int vb) {
        const bf16_t* Vts = smem + 2 * KELEMS + vb * VELEMS;
#pragma unroll
        for (int s = 0; s < 2; ++s) {
            i32x2 s02 = __builtin_amdgcn_permlane32_swap((int)pk[4 * s + 0],
                                                         (int)pk[4 * s + 2], false, false);
            i32x2 s13 = __builtin_amdgcn_permlane32_swap((int)pk[4 * s + 1],
                                                         (int)pk[4 * s + 3], false, false);
            union { uint32_t u[4]; bf16x8 v; } w;
            w.u[0] = (uint32_t)s02[0];
            w.u[1] = (uint32_t)s13[0];
            w.u[2] = (uint32_t)s02[1];
            w.u[3] = (uint32_t)s13[1];
#pragma unroll
            for (int dt = 0; dt < 4; ++dt) {
                bf16x8 a = *(const bf16x8*)(Vts + (dt * 32 + l32) * 64 +
                                            ((4 * wk + 2 * s + hi) ^ sw7) * 8);
                Oacc[dt] = __builtin_amdgcn_mfma_f32_32x32x16_bf16(a, w.v, Oacc[dt], 0, 0, 0);
            }
        }
    };

    uint32_t pkPrev[8];
    stageK(0, 0);
    stageV(0, 0);
    for (int kt = 0; kt < 32; ++kt) {
        const int cur = kt & 1;
        __syncthreads();                 // K[cur],V[cur] (and stageV(kt)) drained
        if (kt + 1 < 32) stageK(kt + 1, cur ^ 1);

        const bf16_t* Ks = smem + cur * KELEMS;

        // S^T = K Q^T over this wave's 32 keys: two independent 4-chains
        f32x16 sf0, sf1;
#pragma unroll
        for (int r = 0; r < 16; ++r) { sf0[r] = 0.f; sf1[r] = 0.f; }
#pragma unroll
        for (int ks = 0; ks < 4; ++ks) {
            bf16x8 a0 = *(const bf16x8*)(Ks + (wk * 32 + l32) * 128 +
                                         ((2 * ks + hi) ^ swK) * 8);
            bf16x8 a1 = *(const bf16x8*)(Ks + (wk * 32 + l32) * 128 +
                                         ((2 * (ks + 4) + hi) ^ swK) * 8);
            sf0 = __builtin_amdgcn_mfma_f32_32x32x16_bf16(a0, qf[ks], sf0, 0, 0, 0);
            sf1 = __builtin_amdgcn_mfma_f32_32x32x16_bf16(a1, qf[ks + 4], sf1, 0, 0, 0);
        }

        // PV for tile kt-1 (lagged): V in buffer cur^1. Independent of the
        // QK chain above -> MFMA pipe stays fed while sf finishes.
        if (kt > 0) pv(pkPrev, cur ^ 1);

        __syncthreads();                 // PV readers of V[cur^1] done
        if (kt + 1 < 32) stageV(kt + 1, cur ^ 1);

        // softmax(kt): register-only, runs after stageV issue -> hides V load.
        float rs0 = 0.f, rs1 = 0.f;
#pragma unroll
        for (int a4 = 0; a4 < 4; ++a4) {
            float p0 = exp2f(sf0[4 * a4 + 0] + sf1[4 * a4 + 0]);
            float p1 = exp2f(sf0[4 * a4 + 1] + sf1[4 * a4 + 1]);
            float p2 = exp2f(sf0[4 * a4 + 2] + sf1[4 * a4 + 2]);
            float p3 = exp2f(sf0[4 * a4 + 3] + sf1[4 * a4 + 3]);
            rs0 += p0 + p1;
            rs1 += p2 + p3;
            pkPrev[a4 * 2 + 0] = pack2(p0, p1);
            pkPrev[a4 * 2 + 1] = pack2(p2, p3);
        }
        l_i += rs0 + rs1;
    }

    // final PV for kt=31: V(31) in buffer 1, untouched since staged
    pv(pkPrev, 1);

    // ---- merge the two k-waves of each wq: l = l0+l1, O = (O0+O1)/l ----
    __syncthreads();
    l_i += __shfl_xor(l_i, 32);
    float* ml = (float*)smem;    // [8 waves][32q] = 1KB
    if (hi == 0) ml[wv * 32 + l32] = l_i;
    __syncthreads();
    float linv = 1.0f / (l_i + ml[(wv ^ 1) * 32 + l32]);
    __syncthreads();  // done reading ml; reuse full smem for O-sum

    float* Op = (float*)smem;  // [4 wq][128 d][32 q] fp32 = 64 KB (exact fit)
    if (wk == 1) {
#pragma unroll
        for (int dt = 0; dt < 4; ++dt)
#pragma unroll
            for (int r = 0; r < 16; ++r) {
                int d = dt * 32 + (r & 3) + 8 * (r >> 2) + 4 * hi;
                Op[(wq * 128 + d) * 32 + l32] = Oacc[dt][r];
            }
    }
    __syncthreads();
    if (wk == 0) {
#pragma unroll
        for (int dt = 0; dt < 4; ++dt)
#pragma unroll
            for (int r = 0; r < 16; ++r) {
                int d = dt * 32 + (r & 3) + 8 * (r >> 2) + 4 * hi;
                Oacc[dt][r] = (Oacc[dt][r] + Op[(wq * 128 + d) * 32 + l32]) * linv;
            }
    }
    __syncthreads();  // Op consumed; reuse LDS for transpose staging

    if (wk == 0) {
        // O^T -> O transpose via LDS (per wq wave, 8 KB each), rotated cols
        uint32_t* Os = (uint32_t*)smem + wq * 2048;  // 32 q-rows x 64 u32
#pragma unroll
        for (int dt = 0; dt < 4; ++dt)
#pragma unroll
            for (int a4 = 0; a4 < 4; ++a4) {
                uint32_t q0 = pack2(Oacc[dt][4 * a4 + 0], Oacc[dt][4 * a4 + 1]);
                uint32_t q1 = pack2(Oacc[dt][4 * a4 + 2], Oacc[dt][4 * a4 + 3]);
                int d2 = 16 * dt + 4 * a4 + 2 * hi;
                Os[l32 * 64 + ((d2 + 2 * l32) & 63)] = q0;
                Os[l32 * 64 + ((d2 + 1 + 2 * l32) & 63)] = q1;
            }
#pragma unroll
        for (int r = 0; r < 32; ++r) {
            uint32_t v = Os[r * 64 + ((lane + 2 * r) & 63)];
            uint32_t* orow = (uint32_t*)(O + (size_t)(qrow0 + wq * 32 + r) * HO + hoff);
            orow[lane] = v;
        }
    }
}

// ---------- launch ----------
extern "C" void kernel_launch(void* const* d_in, const int* in_sizes, int n_in,
                              void* d_out, int out_size, void* d_ws, size_t ws_size,
                              hipStream_t stream) {
    const float* x  = (const float*)d_in[0];
    const float* Wq = (const float*)d_in[1];
    const float* bq = (const float*)d_in[2];
    const float* Wk = (const float*)d_in[3];
    const float* bk = (const float*)d_in[4];
    const float* Wv = (const float*)d_in[5];
    const float* bv = (const float*)d_in[6];
    const float* Wo = (const float*)d_in[7];
    const float* bo = (const float*)d_in[8];
    float* out = (float*)d_out;

    const int T = 4096;          // B*S tokens
    const int H = 2048;          // hidden
    const float SL2E = 0.088388347688f * 1.44269504089f;  // log2(e)/sqrt(128)
    bf16_t* ws  = (bf16_t*)d_ws;
    bf16_t* xb  = ws;                         // T*H
    bf16_t* wqb = xb  + (size_t)T * H;        // H*H (Wq; Wk/Wv/Wo follow contiguously)
    bf16_t* wkb = wqb + (size_t)H * H;
    bf16_t* wvb = wkb + (size_t)H * H;
    bf16_t* wob = wvb + (size_t)H * H;
    bf16_t* QKb = wob + (size_t)H * H;        // T x 4096 (cols 0..2047=Q, 2048..4095=K)
    bf16_t* Vtb = QKb + (size_t)T * 2 * H;    // H x T (V transposed: feature-major)
    bf16_t* Ab  = Vtb + (size_t)H * T;        // T*H attention context
    size_t need = (size_t)(Ab + (size_t)T * H - ws) * sizeof(bf16_t);
    if (ws_size < need) return;

    cvt_f32_bf16<<<T * H / 2048, 256, 0, stream>>>(x, xb);
    cvt4_f32_bf16<<<dim3(H * H / 2048, 4), 256, 0, stream>>>(Wq, Wk, Wv, Wo, wqb, H * H);

    // merged Q|K projection: 256^2 8-phase kernel, 16x16 = 256 blocks.
    // Q half (cols < H) pre-scaled by log2(e)/sqrt(d) for the softmax.
    gemm256<false><<<(T / 256) * (4096 / 256), 512, 0, stream>>>(
        xb, wqb, bq, bk, H, SL2E, 1.0f, nullptr, QKb, T, 4096, H, 4096);

    // V^T = Wv * x^T : swap operands, bias per row (feature), ldc = T
    dim3 gv(H / 128, T / 128);
    gemm_bt<false, true><<<gv, 256, 0, stream>>>(wvb, xb, bv, nullptr, 0, 1.0f, 1.0f,
                                                 nullptr, Vtb, H, T, H, T);

    flash_attn<<<512, 512, 0, stream>>>(QKb, QKb + H, Vtb, Ab);

    dim3 go(T / 128, H / 128);
    gemm_bt<true, false><<<go, 256, 0, stream>>>(Ab, wob, bo, nullptr, H, 1.0f, 1.0f,
                                                 out, nullptr, T, H, H, H);
}

// Round 10
// 398.381 us; speedup vs baseline: 1.0181x; 1.0181x over previous
//
#include <hip/hip_runtime.h>
#include <hip/hip_bf16.h>
#include <stdint.h>

// ---------- types ----------
typedef __bf16 bf16_t;
typedef __attribute__((ext_vector_type(8))) __bf16 bf16x8;   // MFMA A/B frag (4 VGPR)
typedef __attribute__((ext_vector_type(4))) float floatx4;   // 16x16 C frag
typedef __attribute__((ext_vector_type(16))) float f32x16;   // 32x32 C frag
typedef __attribute__((ext_vector_type(2))) int i32x2;

typedef __attribute__((address_space(1))) const unsigned int gu32_t;
typedef __attribute__((address_space(3))) unsigned int lu32_t;

// async global->LDS, 16B per lane; LDS dest = wave-uniform base + lane*16
__device__ __forceinline__ void async16(const void* g, void* l) {
    __builtin_amdgcn_global_load_lds((gu32_t*)g, (lu32_t*)l, 16, 0, 0);
}

__device__ __forceinline__ uint32_t pack2(float lo, float hi) {
    union { bf16_t h[2]; uint32_t u; } cv;
    cv.h[0] = (bf16_t)lo; cv.h[1] = (bf16_t)hi;
    return cv.u;
}

// ---------- fp32 -> bf16 convert ----------
__global__ __launch_bounds__(256) void cvt_f32_bf16(const float* __restrict__ in,
                                                    bf16_t* __restrict__ out) {
    int i = (blockIdx.x * 256 + threadIdx.x) * 8;
    float4 a = *(const float4*)(in + i);
    float4 b = *(const float4*)(in + i + 4);
    bf16x8 v;
    v[0] = (bf16_t)a.x; v[1] = (bf16_t)a.y; v[2] = (bf16_t)a.z; v[3] = (bf16_t)a.w;
    v[4] = (bf16_t)b.x; v[5] = (bf16_t)b.y; v[6] = (bf16_t)b.z; v[7] = (bf16_t)b.w;
    *(bf16x8*)(out + i) = v;
}

// 4 equal-size weight matrices in one dispatch (blockIdx.y selects source)
__global__ __launch_bounds__(256) void cvt4_f32_bf16(const float* __restrict__ w0,
                                                     const float* __restrict__ w1,
                                                     const float* __restrict__ w2,
                                                     const float* __restrict__ w3,
                                                     bf16_t* __restrict__ out,
                                                     int elems) {
    const float* srcs[4] = {w0, w1, w2, w3};
    const float* in = srcs[blockIdx.y];
    bf16_t* o = out + (size_t)blockIdx.y * elems;
    int i = (blockIdx.x * 256 + threadIdx.x) * 8;
    float4 a = *(const float4*)(in + i);
    float4 b = *(const float4*)(in + i + 4);
    bf16x8 v;
    v[0] = (bf16_t)a.x; v[1] = (bf16_t)a.y; v[2] = (bf16_t)a.z; v[3] = (bf16_t)a.w;
    v[4] = (bf16_t)b.x; v[5] = (bf16_t)b.y; v[6] = (bf16_t)b.z; v[7] = (bf16_t)b.w;
    *(bf16x8*)(o + i) = v;
}

// ---------- GEMM 128x128 (m97 structure, measured-good for 2048-dim V/O) ---
template <bool OUT_F32, bool BIAS_ROW>
__global__ __launch_bounds__(256) void gemm_bt(const bf16_t* __restrict__ A,
                                               const bf16_t* __restrict__ B,
                                               const float* __restrict__ bias,
                                               const float* __restrict__ bias2,
                                               int nsplit, float scaleA, float scaleB,
                                               float* __restrict__ Cf,
                                               bf16_t* __restrict__ Cb,
                                               int M, int N, int K, int ldc) {
    __shared__ bf16_t As[128 * 64];
    __shared__ bf16_t Bs[128 * 64];
    const int tid = threadIdx.x;
    const int wave = tid >> 6, lane = tid & 63;
    const int quad = lane >> 4, l16 = lane & 15;
    const int wm = (wave >> 1) * 64, wn = (wave & 1) * 64;
    const int tm = blockIdx.x * 128, tn = blockIdx.y * 128;

    floatx4 acc[4][4];
#pragma unroll
    for (int i = 0; i < 4; ++i)
#pragma unroll
        for (int j = 0; j < 4; ++j) acc[i][j] = floatx4{0.f, 0.f, 0.f, 0.f};

    const bf16_t* Abase = A + (size_t)tm * K;
    const bf16_t* Bbase = B + (size_t)tn * K;
    const int sw = l16 & 7;

    for (int kk = 0; kk < K; kk += 64) {
#pragma unroll
        for (int it = 0; it < 4; ++it) {
            int chunk = it * 256 + tid;
            int r = chunk >> 3, c = chunk & 7;
            int c2 = c ^ (r & 7);
            async16(Abase + r * K + kk + c2 * 8, As + (it * 256 + wave * 64) * 8);
            async16(Bbase + r * K + kk + c2 * 8, Bs + (it * 256 + wave * 64) * 8);
        }
        __syncthreads();
#pragma unroll
        for (int ks = 0; ks < 2; ++ks) {
            bf16x8 af[4], bf[4];
#pragma unroll
            for (int mt = 0; mt < 4; ++mt)
                af[mt] = *(const bf16x8*)(As + (wm + mt * 16 + l16) * 64 +
                                          ((ks * 4 + quad) ^ sw) * 8);
#pragma unroll
            for (int nt = 0; nt < 4; ++nt)
                bf[nt] = *(const bf16x8*)(Bs + (wn + nt * 16 + l16) * 64 +
                                          ((ks * 4 + quad) ^ sw) * 8);
#pragma unroll
            for (int mt = 0; mt < 4; ++mt)
#pragma unroll
                for (int nt = 0; nt < 4; ++nt)
                    acc[mt][nt] = __builtin_amdgcn_mfma_f32_16x16x32_bf16(af[mt], bf[nt],
                                                                          acc[mt][nt], 0, 0, 0);
        }
        __syncthreads();
    }
#pragma unroll
    for (int mt = 0; mt < 4; ++mt)
#pragma unroll
        for (int nt = 0; nt < 4; ++nt)
#pragma unroll
            for (int r = 0; r < 4; ++r) {
                int row = tm + wm + mt * 16 + quad * 4 + r;
                int col = tn + wn + nt * 16 + l16;
                float bv = BIAS_ROW ? bias[row]
                                    : (col < nsplit ? bias[col] : bias2[col - nsplit]);
                float v = acc[mt][nt][r] + bv;
                if (!BIAS_ROW) v *= (col < nsplit ? scaleA : scaleB);
                if (OUT_F32) Cf[(size_t)row * ldc + col] = v;
                else Cb[(size_t)row * ldc + col] = (bf16_t)v;
            }
}

// ---------- GEMM 256x256, 8-phase counted schedule (QK projection only) ----
// EXACT R4 version (verified -25us vs gemm_bt; R7/R8 variants both regressed).
template <bool OUT_F32>
__global__ __launch_bounds__(512, 2) void gemm256(const bf16_t* __restrict__ A,
                                                  const bf16_t* __restrict__ B,
                                                  const float* __restrict__ bias,
                                                  const float* __restrict__ bias2,
                                                  int nsplit, float scaleA, float scaleB,
                                                  float* __restrict__ Cf,
                                                  bf16_t* __restrict__ Cb,
                                                  int M, int N, int K, int ldc) {
    __shared__ bf16_t As[2][256 * 64];   // 64 KB
    __shared__ bf16_t Bs[2][256 * 64];   // 64 KB
    const int tid = threadIdx.x;
    const int wave = tid >> 6, lane = tid & 63;
    const int quad = lane >> 4, l16 = lane & 15;
    const int wr = wave >> 2, wc = wave & 3;           // 2 x 4 wave grid
    const int nbx = M >> 8;
    const int nwg = nbx * (N >> 8);
    const int xcd = blockIdx.x & 7, idx = blockIdx.x >> 3;
    const int per = nwg >> 3;                           // nwg % 8 == 0 here
    const int wg = xcd * per + idx;
    const int tm = (wg % nbx) * 256, tn = (wg / nbx) * 256;

    floatx4 acc[8][4];
#pragma unroll
    for (int i = 0; i < 8; ++i)
#pragma unroll
        for (int j = 0; j < 4; ++j) acc[i][j] = floatx4{0.f, 0.f, 0.f, 0.f};

    const bf16_t* Abase = A + (size_t)tm * K;
    const bf16_t* Bbase = B + (size_t)tn * K;
    const int sw = l16 & 7;
    const int NT = K >> 6;

    auto stageA = [&](int kk, int b) {
#pragma unroll
        for (int it = 0; it < 4; ++it) {
            int chunk = it * 512 + tid;            // 256 rows x 8 chunks
            int r = chunk >> 3, c = chunk & 7;
            int c2 = c ^ (r & 7);
            async16(Abase + (size_t)r * K + kk + c2 * 8, As[b] + chunk * 8);
        }
    };
    auto stageB = [&](int kk, int b) {
#pragma unroll
        for (int it = 0; it < 4; ++it) {
            int chunk = it * 512 + tid;
            int r = chunk >> 3, c = chunk & 7;
            int c2 = c ^ (r & 7);
            async16(Bbase + (size_t)r * K + kk + c2 * 8, Bs[b] + chunk * 8);
        }
    };

    // prologue: tile 0 fully staged & visible
    stageA(0, 0);
    stageB(0, 0);
    asm volatile("s_waitcnt vmcnt(0)" ::: "memory");
    __builtin_amdgcn_s_barrier();
    __builtin_amdgcn_sched_barrier(0);

    for (int t = 0; t < NT; ++t) {
        const int cur = t & 1;
        const bf16_t* Asb = As[cur];
        const bf16_t* Bsb = Bs[cur];
        const int nk = (t + 1) << 6;
        const bool more = (t + 1 < NT);
#pragma unroll
        for (int p = 0; p < 4; ++p) {
            const int mh = p >> 1, nh = p & 1;     // quadrant: rows mh*64, cols nh*32
            bf16x8 af[4][2], bg[2][2];
#pragma unroll
            for (int mt = 0; mt < 4; ++mt) {
                int row = wr * 128 + mh * 64 + mt * 16 + l16;
#pragma unroll
                for (int ks = 0; ks < 2; ++ks)
                    af[mt][ks] = *(const bf16x8*)(Asb + row * 64 + ((ks * 4 + quad) ^ sw) * 8);
            }
#pragma unroll
            for (int nt = 0; nt < 2; ++nt) {
                int col = wc * 64 + nh * 32 + nt * 16 + l16;
#pragma unroll
                for (int ks = 0; ks < 2; ++ks)
                    bg[nt][ks] = *(const bf16x8*)(Bsb + col * 64 + ((ks * 4 + quad) ^ sw) * 8);
            }
            if (more) {                            // issue-early: full tile ahead
                if (p == 0) stageA(nk, cur ^ 1);
                else if (p == 1) stageB(nk, cur ^ 1);
            }
            __builtin_amdgcn_s_barrier();
            asm volatile("s_waitcnt lgkmcnt(0)" ::: "memory");
            __builtin_amdgcn_sched_barrier(0);
            __builtin_amdgcn_s_setprio(1);
#pragma unroll
            for (int ks = 0; ks < 2; ++ks)
#pragma unroll
                for (int mt = 0; mt < 4; ++mt)
#pragma unroll
                    for (int nt = 0; nt < 2; ++nt)
                        acc[mh * 4 + mt][nh * 2 + nt] =
                            __builtin_amdgcn_mfma_f32_16x16x32_bf16(
                                af[mt][ks], bg[nt][ks], acc[mh * 4 + mt][nh * 2 + nt], 0, 0, 0);
            __builtin_amdgcn_s_setprio(0);
            if (p == 3 && more)                    // boundary: next tile landed
                asm volatile("s_waitcnt vmcnt(0)" ::: "memory");
            __builtin_amdgcn_s_barrier();
            __builtin_amdgcn_sched_barrier(0);
        }
    }

#pragma unroll
    for (int am = 0; am < 8; ++am)
#pragma unroll
        for (int an = 0; an < 4; ++an)
#pragma unroll
            for (int r = 0; r < 4; ++r) {
                int row = tm + wr * 128 + (am >> 2) * 64 + (am & 3) * 16 + quad * 4 + r;
                int col = tn + wc * 64 + (an >> 1) * 32 + (an & 1) * 16 + l16;
                float bv = col < nsplit ? bias[col] : bias2[col - nsplit];
                float v = (acc[am][an][r] + bv) * (col < nsplit ? scaleA : scaleB);
                if (OUT_F32) Cf[(size_t)row * ldc + col] = v;
                else Cb[(size_t)row * ldc + col] = (bf16_t)v;
            }
}

// ---------- flash attention: 512-thr R9 structure + VALU-trimmed kt loop ---
// R15: flash is VALU-issue-bound (VALUBusy 50%, MfmaUtil 27%). All 16 LDS
// read offsets per kt are loop-invariant; precompute them once (kby[8],
// vby[2][4], statically indexed -> registers) and hand-unroll kt by 2 so
// `cur` is a compile-time literal -> every ds_read folds to base+imm, ~zero
// per-iteration address VALU. Schedule/barriers byte-identical to R9.
#define KELEMS (64 * 128)   // 16 KB per K buffer
#define VELEMS (128 * 64)   // 16 KB per V buffer
__global__ __launch_bounds__(512, 2) void flash_attn(const bf16_t* __restrict__ Qp,
                                                     const bf16_t* __restrict__ Kp,
                                                     const bf16_t* __restrict__ Vt,
                                                     bf16_t* __restrict__ O) {
    __shared__ bf16_t smem[2 * KELEMS + 2 * VELEMS];  // K0 K1 V0 V1 = 64 KB
    const int tid = threadIdx.x;
    const int wv = tid >> 6, lane = tid & 63;
    const int hi = lane >> 5, l32 = lane & 31;
    const int wq = wv >> 1, wk = wv & 1;   // 4 q-subtiles x 2 k-halves
    const int LD = 4096, T = 4096, S = 2048, HO = 2048;

    // XCD-aware decode: 512 blocks = 16 qt x 32 grp; gid&7 = XCD.
    const int gid = blockIdx.x;
    const int kq = gid >> 3;
    const int qt = kq & 15;                       // q-tile 0..15 (128 rows)
    const int grp = (gid & 7) + 8 * (kq >> 4);    // group 0..31
    const int hd = grp & 15, bt = grp >> 4;

    const int qrow0 = bt * S + qt * 128;
    const int krow0 = bt * S;
    const int hoff = hd * 128;
    const int sw7 = l32 & 7;
    const int swK = l32 & 15;

    // Q B-frags: B[k][q=l32], k = 16*ks + 8*hi + j, for q-rows wq*32..+32
    bf16x8 qf[8];
    const bf16_t* qptr = Qp + (size_t)(qrow0 + wq * 32 + l32) * LD + hoff + hi * 8;
#pragma unroll
    for (int ks = 0; ks < 8; ++ks) qf[ks] = *(const bf16x8*)(qptr + ks * 16);

    // Loop-invariant LDS byte offsets (statically indexed -> registers)
    int kby[8];
#pragma unroll
    for (int j = 0; j < 8; ++j)
        kby[j] = (wk * 32 + l32) * 256 + (((2 * j + hi) ^ swK) << 4);
    int vby[2][4];
#pragma unroll
    for (int s = 0; s < 2; ++s)
#pragma unroll
        for (int dt = 0; dt < 4; ++dt)
            vby[s][dt] = (dt * 32 + l32) * 128 + (((4 * wk + 2 * s + hi) ^ sw7) << 4);

    float l_i = 0.f;   // linear softmax denominator partial
    f32x16 Oacc[4];    // O^T partial: rows d (128), col q = l32 (AGPR-resident)
#pragma unroll
    for (int dt = 0; dt < 4; ++dt)
#pragma unroll
        for (int r = 0; r < 16; ++r) Oacc[dt][r] = 0.f;

    auto stageK = [&](int kt, int b) {
        int kb = krow0 + kt * 64;
        bf16_t* Ks = smem + b * KELEMS;
#pragma unroll
        for (int it = 0; it < 2; ++it) {
            int chunk = it * 512 + tid;          // 64 rows x 16 slots
            int r = chunk >> 4, c = chunk & 15;
            int c2 = c ^ (r & 15);
            async16(Kp + (size_t)(kb + r) * LD + hoff + c2 * 8, Ks + chunk * 8);
        }
    };
    auto stageV = [&](int kt, int b) {
        int kb = krow0 + kt * 64;
        bf16_t* Vts = smem + 2 * KELEMS + b * VELEMS;
#pragma unroll
        for (int it = 0; it < 2; ++it) {
            int chunk = it * 512 + tid;          // 128 rows x 8 slots
            int r = chunk >> 3, c = chunk & 7;
            int c2 = c ^ (r & 7);
            async16(Vt + (size_t)(hoff + r) * T + kb + c2 * 8, Vts + chunk * 8);
        }
    };

    // PV step: packed P in pk[], V buffer base (bytes) in Vbase
    auto pv = [&](const uint32_t* pk, const char* Vbase) {
#pragma unroll
        for (int s = 0; s < 2; ++s) {
            i32x2 s02 = __builtin_amdgcn_permlane32_swap((int)pk[4 * s + 0],
                                                         (int)pk[4 * s + 2], false, false);
            i32x2 s13 = __builtin_amdgcn_permlane32_swap((int)pk[4 * s + 1],
                                                         (int)pk[4 * s + 3], false, false);
            union { uint32_t u[4]; bf16x8 v; } w;
            w.u[0] = (uint32_t)s02[0];
            w.u[1] = (uint32_t)s13[0];
            w.u[2] = (uint32_t)s02[1];
            w.u[3] = (uint32_t)s13[1];
#pragma unroll
            for (int dt = 0; dt < 4; ++dt) {
                bf16x8 a = *(const bf16x8*)(Vbase + vby[s][dt]);
                Oacc[dt] = __builtin_amdgcn_mfma_f32_32x32x16_bf16(a, w.v, Oacc[dt], 0, 0, 0);
            }
        }
    };

    uint32_t pkPrev[8];
    // kt body; cur passed as compile-time literal via the unrolled caller
    auto kt_body = [&](int kt, int cur) {
        __syncthreads();                 // K[cur],V[cur] (and stageV(kt)) drained
        if (kt + 1 < 32) stageK(kt + 1, cur ^ 1);

        const char* Kb = (const char*)smem + cur * (KELEMS * 2);

        // S^T = K Q^T over this wave's 32 keys: two independent 4-chains
        f32x16 sf0, sf1;
#pragma unroll
        for (int r = 0; r < 16; ++r) { sf0[r] = 0.f; sf1[r] = 0.f; }
#pragma unroll
        for (int ks = 0; ks < 4; ++ks) {
            bf16x8 a0 = *(const bf16x8*)(Kb + kby[ks]);
            bf16x8 a1 = *(const bf16x8*)(Kb + kby[ks + 4]);
            sf0 = __builtin_amdgcn_mfma_f32_32x32x16_bf16(a0, qf[ks], sf0, 0, 0, 0);
            sf1 = __builtin_amdgcn_mfma_f32_32x32x16_bf16(a1, qf[ks + 4], sf1, 0, 0, 0);
        }

        // PV for tile kt-1 (lagged): V in buffer cur^1.
        if (kt > 0)
            pv(pkPrev, (const char*)smem + (2 * KELEMS + (cur ^ 1) * VELEMS) * 2);

        __syncthreads();                 // PV readers of V[cur^1] done
        if (kt + 1 < 32) stageV(kt + 1, cur ^ 1);

        // softmax(kt): register-only, runs after stageV issue -> hides V load.
        float rs0 = 0.f, rs1 = 0.f;
#pragma unroll
        for (int a4 = 0; a4 < 4; ++a4) {
            float p0 = exp2f(sf0[4 * a4 + 0] + sf1[4 * a4 + 0]);
            float p1 = exp2f(sf0[4 * a4 + 1] + sf1[4 * a4 + 1]);
            float p2 = exp2f(sf0[4 * a4 + 2] + sf1[4 * a4 + 2]);
            float p3 = exp2f(sf0[4 * a4 + 3] + sf1[4 * a4 + 3]);
            rs0 += p0 + p1;
            rs1 += p2 + p3;
            pkPrev[a4 * 2 + 0] = pack2(p0, p1);
            pkPrev[a4 * 2 + 1] = pack2(p2, p3);
        }
        l_i += rs0 + rs1;
    };

    stageK(0, 0);
    stageV(0, 0);
    for (int kt = 0; kt < 32; kt += 2) {   // hand-unrolled x2: cur is literal
        kt_body(kt, 0);
        kt_body(kt + 1, 1);
    }

    // final PV for kt=31: V(31) in buffer 1, untouched since staged
    pv(pkPrev, (const char*)smem + (2 * KELEMS + 1 * VELEMS) * 2);

    // ---- merge the two k-waves of each wq: l = l0+l1, O = (O0+O1)/l ----
    __syncthreads();
    l_i += __shfl_xor(l_i, 32);
    float* ml = (float*)smem;    // [8 waves][32q] = 1KB
    if (hi == 0) ml[wv * 32 + l32] = l_i;
    __syncthreads();
    float linv = 1.0f / (l_i + ml[(wv ^ 1) * 32 + l32]);
    __syncthreads();  // done reading ml; reuse full smem for O-sum

    float* Op = (float*)smem;  // [4 wq][128 d][32 q] fp32 = 64 KB (exact fit)
    if (wk == 1) {
#pragma unroll
        for (int dt = 0; dt < 4; ++dt)
#pragma unroll
            for (int r = 0; r < 16; ++r) {
                int d = dt * 32 + (r & 3) + 8 * (r >> 2) + 4 * hi;
                Op[(wq * 128 + d) * 32 + l32] = Oacc[dt][r];
            }
    }
    __syncthreads();
    if (wk == 0) {
#pragma unroll
        for (int dt = 0; dt < 4; ++dt)
#pragma unroll
            for (int r = 0; r < 16; ++r) {
                int d = dt * 32 + (r & 3) + 8 * (r >> 2) + 4 * hi;
                Oacc[dt][r] = (Oacc[dt][r] + Op[(wq * 128 + d) * 32 + l32]) * linv;
            }
    }
    __syncthreads();  // Op consumed; reuse LDS for transpose staging

    if (wk == 0) {
        // O^T -> O transpose via LDS (per wq wave, 8 KB each), rotated cols
        uint32_t* Os = (uint32_t*)smem + wq * 2048;  // 32 q-rows x 64 u32
#pragma unroll
        for (int dt = 0; dt < 4; ++dt)
#pragma unroll
            for (int a4 = 0; a4 < 4; ++a4) {
                uint32_t q0 = pack2(Oacc[dt][4 * a4 + 0], Oacc[dt][4 * a4 + 1]);
                uint32_t q1 = pack2(Oacc[dt][4 * a4 + 2], Oacc[dt][4 * a4 + 3]);
                int d2 = 16 * dt + 4 * a4 + 2 * hi;
                Os[l32 * 64 + ((d2 + 2 * l32) & 63)] = q0;
                Os[l32 * 64 + ((d2 + 1 + 2 * l32) & 63)] = q1;
            }
#pragma unroll
        for (int r = 0; r < 32; ++r) {
            uint32_t v = Os[r * 64 + ((lane + 2 * r) & 63)];
            uint32_t* orow = (uint32_t*)(O + (size_t)(qrow0 + wq * 32 + r) * HO + hoff);
            orow[lane] = v;
        }
    }
}

// ---------- launch ----------
extern "C" void kernel_launch(void* const* d_in, const int* in_sizes, int n_in,
                              void* d_out, int out_size, void* d_ws, size_t ws_size,
                              hipStream_t stream) {
    const float* x  = (const float*)d_in[0];
    const float* Wq = (const float*)d_in[1];
    const float* bq = (const float*)d_in[2];
    const float* Wk = (const float*)d_in[3];
    const float* bk = (const float*)d_in[4];
    const float* Wv = (const float*)d_in[5];
    const float* bv = (const float*)d_in[6];
    const float* Wo = (const float*)d_in[7];
    const float* bo = (const float*)d_in[8];
    float* out = (float*)d_out;

    const int T = 4096;          // B*S tokens
    const int H = 2048;          // hidden
    const float SL2E = 0.088388347688f * 1.44269504089f;  // log2(e)/sqrt(128)
    bf16_t* ws  = (bf16_t*)d_ws;
    bf16_t* xb  = ws;                         // T*H
    bf16_t* wqb = xb  + (size_t)T * H;        // H*H (Wq; Wk/Wv/Wo follow contiguously)
    bf16_t* wkb = wqb + (size_t)H * H;
    bf16_t* wvb = wkb + (size_t)H * H;
    bf16_t* wob = wvb + (size_t)H * H;
    bf16_t* QKb = wob + (size_t)H * H;        // T x 4096 (cols 0..2047=Q, 2048..4095=K)
    bf16_t* Vtb = QKb + (size_t)T * 2 * H;    // H x T (V transposed: feature-major)
    bf16_t* Ab  = Vtb + (size_t)H * T;        // T*H attention context
    size_t need = (size_t)(Ab + (size_t)T * H - ws) * sizeof(bf16_t);
    if (ws_size < need) return;

    cvt_f32_bf16<<<T * H / 2048, 256, 0, stream>>>(x, xb);
    cvt4_f32_bf16<<<dim3(H * H / 2048, 4), 256, 0, stream>>>(Wq, Wk, Wv, Wo, wqb, H * H);

    // merged Q|K projection: 256^2 8-phase kernel, 16x16 = 256 blocks.
    // Q half (cols < H) pre-scaled by log2(e)/sqrt(d) for the softmax.
    gemm256<false><<<(T / 256) * (4096 / 256), 512, 0, stream>>>(
        xb, wqb, bq, bk, H, SL2E, 1.0f, nullptr, QKb, T, 4096, H, 4096);

    // V^T = Wv * x^T : swap operands, bias per row (feature), ldc = T
    dim3 gv(H / 128, T / 128);
    gemm_bt<false, true><<<gv, 256, 0, stream>>>(wvb, xb, bv, nullptr, 0, 1.0f, 1.0f,
                                                 nullptr, Vtb, H, T, H, T);

    flash_attn<<<512, 512, 0, stream>>>(QKb, QKb + H, Vtb, Ab);

    dim3 go(T / 128, H / 128);
    gemm_bt<true, false><<<go, 256, 0, stream>>>(Ab, wob, bo, nullptr, H, 1.0f, 1.0f,
                                                 out, nullptr, T, H, H, H);
}